// Round 1
// baseline (296.129 us; speedup 1.0000x reference)
//
#include <hip/hip_runtime.h>
#include <hip/hip_bf16.h>
#include <hip/hip_fp16.h>

#define N_NODES 50000
#define N_EDGES 800000
#define NUM_GRAPHS 256
#define D 64
#define EPS 1e-5f
#define N_PART 8
#define PART_SIZE (N_NODES / N_PART)   // 6250
#define SCAT_CHUNKS 512
#define SCAT_GRID (SCAT_CHUNKS * N_PART)
#define GEMM_BLOCKS ((N_NODES + 63) / 64)   // 782
#define WP 72   // padded LDS row stride in halves (16B-aligned, conflict-breaking)

typedef _Float16 half8_t __attribute__((ext_vector_type(8)));
typedef _Float16 half4_t __attribute__((ext_vector_type(4)));
typedef float f32x4 __attribute__((ext_vector_type(4)));

// ---------------------------------------------------------------------------
// Shared per-node aggregation: pull 16B/lane gathers from the fp16 XW table,
// apply dinv[r]=rsqrt(cnt[r]+1) per edge (table is UNSCALED now), self-loop
// via sub==0. Butterfly-reduce across the 8 edge-subs; all lanes end with the
// full 8-feature partial (accA=feats i4*4.., accB for sub=1 half).
__device__ __forceinline__ void agg_node(const uint4* __restrict__ xw8,
        const int* __restrict__ cnt, const unsigned short* __restrict__ ssrc,
        int cap, int c, int sub, int f2,
        float4& accA, float4& accB, float& dc) {
    int n = cnt[c];
    if (n > cap) n = cap;
    dc = rsqrtf((float)n + 1.0f);
    size_t sbase = (size_t)c * cap;
    accA = make_float4(0.f, 0.f, 0.f, 0.f);
    accB = accA;
    if (sub == 0) {   // self-loop: dinv[c]*xw[c] (epilogue multiplies by dc again)
        uint4 v = xw8[(size_t)c * 8 + f2];
        const __half2* hp = (const __half2*)&v;
        float2 q0 = __half22float2(hp[0]), q1 = __half22float2(hp[1]);
        float2 q2 = __half22float2(hp[2]), q3 = __half22float2(hp[3]);
        accA.x = dc * q0.x; accA.y = dc * q0.y;
        accA.z = dc * q1.x; accA.w = dc * q1.y;
        accB.x = dc * q2.x; accB.y = dc * q2.y;
        accB.z = dc * q3.x; accB.w = dc * q3.y;
    }
    for (int e0 = 0; e0 < n; e0 += 8) {
        int e = e0 + sub;
        if (e < n) {
            int r = (int)ssrc[sbase + e];
            float wr = rsqrtf((float)cnt[r] + 1.0f);
            uint4 v = xw8[(size_t)r * 8 + f2];
            const __half2* hp = (const __half2*)&v;
            float2 q0 = __half22float2(hp[0]), q1 = __half22float2(hp[1]);
            float2 q2 = __half22float2(hp[2]), q3 = __half22float2(hp[3]);
            accA.x += wr * q0.x; accA.y += wr * q0.y;
            accA.z += wr * q1.x; accA.w += wr * q1.y;
            accB.x += wr * q2.x; accB.y += wr * q2.y;
            accB.z += wr * q3.x; accB.w += wr * q3.y;
        }
    }
#pragma unroll
    for (int off = 8; off < 64; off <<= 1) {
        accA.x += __shfl_xor(accA.x, off, 64); accA.y += __shfl_xor(accA.y, off, 64);
        accA.z += __shfl_xor(accA.z, off, 64); accA.w += __shfl_xor(accA.w, off, 64);
        accB.x += __shfl_xor(accB.x, off, 64); accB.y += __shfl_xor(accB.y, off, 64);
        accB.z += __shfl_xor(accB.z, off, 64); accB.w += __shfl_xor(accB.w, off, 64);
    }
}

__device__ __forceinline__ float4 bn_relu4(float4 acc, float dc, int i4,
        const float* __restrict__ b, const float* __restrict__ g,
        const float* __restrict__ bb, const float* __restrict__ m,
        const float* __restrict__ var) {
    float4 b4  = ((const float4*)b)[i4];
    float4 m4  = ((const float4*)m)[i4];
    float4 v4_ = ((const float4*)var)[i4];
    float4 g4  = ((const float4*)g)[i4];
    float4 bb4 = ((const float4*)bb)[i4];
    float4 h;
    h.x = (acc.x * dc + b4.x - m4.x) * (1.0f / sqrtf(v4_.x + EPS)) * g4.x + bb4.x;
    h.y = (acc.y * dc + b4.y - m4.y) * (1.0f / sqrtf(v4_.y + EPS)) * g4.y + bb4.y;
    h.z = (acc.z * dc + b4.z - m4.z) * (1.0f / sqrtf(v4_.z + EPS)) * g4.z + bb4.z;
    h.w = (acc.w * dc + b4.w - m4.w) * (1.0f / sqrtf(v4_.w + EPS)) * g4.w + bb4.w;
    h.x = h.x > 0.f ? h.x : 0.f;
    h.y = h.y > 0.f ? h.y : 0.f;
    h.z = h.z > 0.f ? h.z : 0.f;
    h.w = h.w > 0.f ? h.w : 0.f;
    return h;
}

// ---------------------------------------------------------------------------
// 1) FUSED: slotted-CSR build (XCD-partitioned, int4-vectorized col scan)
//    running CONCURRENTLY with gemm0 (Yh = X@W0, fp16, UNSCALED — dinv applied
//    per-edge in agg, so gemm no longer depends on cnt).
__global__ __launch_bounds__(256) void build_gemm_kernel(
        const int* __restrict__ ei, int* __restrict__ cnt,
        unsigned short* __restrict__ ssrc, int cap,
        const float* __restrict__ X, const float* __restrict__ W,
        __half* __restrict__ Yh) {
    __shared__ _Float16 Xs[64 * WP];   // [row][k]
    __shared__ _Float16 Wt[64 * WP];   // [n][k]
    if (blockIdx.x < SCAT_GRID) {
        // ---- scatter part (blocks 0..4095 keep blockIdx&7 -> XCD affinity) ----
        int p     = blockIdx.x & (N_PART - 1);
        int chunk = blockIdx.x >> 3;
        const int per = (((N_EDGES + SCAT_CHUNKS - 1) / SCAT_CHUNKS) + 3) & ~3;  // 1564
        int lo = chunk * per;
        int hi = lo + per; if (hi > N_EDGES) hi = N_EDGES;
        for (int e4 = lo + (int)threadIdx.x * 4; e4 < hi; e4 += 1024) {
            int4 c4 = *(const int4*)&ei[N_EDGES + e4];   // 16B-aligned: lo%4==0, E%4==0
            const int* cc = (const int*)&c4;
#pragma unroll
            for (int k = 0; k < 4; k++) {
                int e = e4 + k;
                if (e < hi) {
                    int c = cc[k];
                    if (c / PART_SIZE == p) {
                        int r = ei[e];
                        int pos = atomicAdd(&cnt[c], 1);
                        if (pos < cap) ssrc[(size_t)c * cap + pos] = (unsigned short)r;
                    }
                }
            }
        }
        return;
    }
    // ---- gemm0 part ----
    int tid  = threadIdx.x;
    int base = (blockIdx.x - SCAT_GRID) * 64;
    for (int i = tid; i < 4096; i += 256) {       // stage W^T fp16
        int k = i >> 6, n = i & 63;
        Wt[n * WP + k] = (_Float16)W[i];
    }
    for (int i = tid; i < 1024; i += 256) {       // stage X rows fp16
        int r = i >> 4, c4 = (i & 15) * 4;
        float4 xv = (base + r < N_NODES)
            ? ((const float4*)X)[(size_t)(base + r) * 16 + (i & 15)]
            : make_float4(0.f, 0.f, 0.f, 0.f);
        _Float16* dst = &Xs[r * WP + c4];
        dst[0] = (_Float16)xv.x; dst[1] = (_Float16)xv.y;
        dst[2] = (_Float16)xv.z; dst[3] = (_Float16)xv.w;
    }
    __syncthreads();
    int wave  = tid >> 6;
    int lane  = tid & 63;
    int m     = lane & 15;
    int q     = lane >> 4;
    int row16 = wave * 16;
    half8_t a0 = *(const half8_t*)&Xs[(row16 + m) * WP + q * 8];
    half8_t a1 = *(const half8_t*)&Xs[(row16 + m) * WP + 32 + q * 8];
    f32x4 acc[4];
#pragma unroll
    for (int ct = 0; ct < 4; ct++) {
        half8_t b0 = *(const half8_t*)&Wt[(ct * 16 + m) * WP + q * 8];
        half8_t b1 = *(const half8_t*)&Wt[(ct * 16 + m) * WP + 32 + q * 8];
        f32x4 c = {0.f, 0.f, 0.f, 0.f};
        c = __builtin_amdgcn_mfma_f32_16x16x32_f16(a0, b0, c, 0, 0, 0);
        c = __builtin_amdgcn_mfma_f32_16x16x32_f16(a1, b1, c, 0, 0, 0);
        acc[ct] = c;
    }
#pragma unroll
    for (int ct = 0; ct < 4; ct++) {
#pragma unroll
        for (int reg = 0; reg < 4; reg++) {
            int row = base + row16 + q * 4 + reg;
            if (row < N_NODES)
                Yh[(size_t)row * 64 + ct * 16 + m] = (__half)acc[ct][reg];
        }
    }
}

// ---------------------------------------------------------------------------
// 2) FUSED: agg0 + self-loop + bias + BN + ReLU  →  h0 in LDS (fp16)  →
//    in-block MFMA GEMM with W1  →  xwh_out (fp16, unscaled).
//    512 threads = 8 waves; wave-per-node over 8 nodes (64-node tile/block).
__global__ __launch_bounds__(512) void agg_gemm_kernel(
        const __half* __restrict__ xwh_in, const int* __restrict__ cnt,
        const unsigned short* __restrict__ ssrc, int cap,
        const float* __restrict__ b, const float* __restrict__ g,
        const float* __restrict__ bb, const float* __restrict__ m,
        const float* __restrict__ var,
        const float* __restrict__ W, __half* __restrict__ xwh_out, int N) {
    __shared__ _Float16 Xs[64 * WP];   // h0 rows (fp16)
    __shared__ _Float16 Wt[64 * WP];   // W1^T
    int tid = threadIdx.x;
    for (int i = tid; i < 4096; i += 512) {       // stage W1^T (barrier below covers)
        int k = i >> 6, n = i & 63;
        Wt[n * WP + k] = (_Float16)W[i];
    }
    int wave = tid >> 6, lane = tid & 63;
    int sub = lane >> 3, f2 = lane & 7;
    int base = blockIdx.x * 64;
    const uint4* xw8 = (const uint4*)xwh_in;
    for (int i = 0; i < 8; i++) {
        int idx = wave * 8 + i;
        int c = base + idx;
        if (c < N) {
            float4 accA, accB; float dc;
            agg_node(xw8, cnt, ssrc, cap, c, sub, f2, accA, accB, dc);
            if (sub < 2) {
                int i4 = 2 * f2 + sub;
                float4 h = bn_relu4(sub ? accB : accA, dc, i4, b, g, bb, m, var);
                half4_t hv = {(_Float16)h.x, (_Float16)h.y, (_Float16)h.z, (_Float16)h.w};
                *(half4_t*)&Xs[idx * WP + i4 * 4] = hv;
            }
        } else if (sub < 2) {
            int i4 = 2 * f2 + sub;
            half4_t hv = {(_Float16)0.f, (_Float16)0.f, (_Float16)0.f, (_Float16)0.f};
            *(half4_t*)&Xs[idx * WP + i4 * 4] = hv;
        }
    }
    __syncthreads();
    // GEMM: 16 (row16,ct) tiles over 8 waves, 2 tiles each.
    int m_ = lane & 15, q = lane >> 4;
#pragma unroll
    for (int tt = 0; tt < 2; tt++) {
        int t   = wave + tt * 8;
        int r16 = (t >> 2) * 16;
        int ct  = t & 3;
        half8_t a0 = *(const half8_t*)&Xs[(r16 + m_) * WP + q * 8];
        half8_t a1 = *(const half8_t*)&Xs[(r16 + m_) * WP + 32 + q * 8];
        half8_t b0 = *(const half8_t*)&Wt[(ct * 16 + m_) * WP + q * 8];
        half8_t b1 = *(const half8_t*)&Wt[(ct * 16 + m_) * WP + 32 + q * 8];
        f32x4 cc = {0.f, 0.f, 0.f, 0.f};
        cc = __builtin_amdgcn_mfma_f32_16x16x32_f16(a0, b0, cc, 0, 0, 0);
        cc = __builtin_amdgcn_mfma_f32_16x16x32_f16(a1, b1, cc, 0, 0, 0);
#pragma unroll
        for (int reg = 0; reg < 4; reg++) {
            int row = base + r16 + q * 4 + reg;
            if (row < N)
                xwh_out[(size_t)row * 64 + ct * 16 + m_] = (__half)cc[reg];
        }
    }
}

// ---------------------------------------------------------------------------
// 3) FUSED: agg1 + bias + BN + ReLU + mean-pool partial sums.
//    batch is sorted → a 64-node block spans <=2 graphs; accumulate in <=4
//    LDS bins, flush with one global atomicAdd per (graph,feat) per block.
__global__ __launch_bounds__(512) void agg_pool_kernel(
        const __half* __restrict__ xwh_in, const int* __restrict__ cnt,
        const unsigned short* __restrict__ ssrc, int cap,
        const float* __restrict__ b, const float* __restrict__ g,
        const float* __restrict__ bb, const float* __restrict__ m,
        const float* __restrict__ var,
        const int* __restrict__ batch, float* __restrict__ sums, int N) {
    __shared__ float gsum[4][64];
    __shared__ int ginfo[2];
    int tid = threadIdx.x;
    if (tid < 256) gsum[tid >> 6][tid & 63] = 0.0f;
    int base = blockIdx.x * 64;
    if (tid == 0) {
        int last = base + 63; if (last >= N) last = N - 1;
        int glo = batch[base];
        ginfo[0] = glo;
        ginfo[1] = batch[last] - glo + 1;
    }
    __syncthreads();
    int glo = ginfo[0], span = ginfo[1];
    int wave = tid >> 6, lane = tid & 63;
    int sub = lane >> 3, f2 = lane & 7;
    const uint4* xw8 = (const uint4*)xwh_in;
    for (int i = 0; i < 8; i++) {
        int idx = wave * 8 + i;
        int c = base + idx;
        if (c >= N) continue;   // wave-uniform
        float4 accA, accB; float dc;
        agg_node(xw8, cnt, ssrc, cap, c, sub, f2, accA, accB, dc);
        if (sub < 2) {
            int i4 = 2 * f2 + sub;
            float4 h = bn_relu4(sub ? accB : accA, dc, i4, b, g, bb, m, var);
            int gid = batch[c];
            if (span <= 4) {
                float* gp = &gsum[gid - glo][i4 * 4];
                atomicAdd(&gp[0], h.x); atomicAdd(&gp[1], h.y);
                atomicAdd(&gp[2], h.z); atomicAdd(&gp[3], h.w);
            } else {   // pathological span: fall back to global atomics
                float* sp = &sums[(size_t)gid * 64 + i4 * 4];
                atomicAdd(&sp[0], h.x); atomicAdd(&sp[1], h.y);
                atomicAdd(&sp[2], h.z); atomicAdd(&sp[3], h.w);
            }
        }
    }
    __syncthreads();
    if (span <= 4 && tid < span * 64) {
        float v = gsum[tid >> 6][tid & 63];
        atomicAdd(&sums[(size_t)(glo + (tid >> 6)) * 64 + (tid & 63)], v);
    }
}

// ---------------------------------------------------------------------------
// 4) head: pooled = sums/count (count via sorted-batch binary search) + MLP.
__global__ __launch_bounds__(256) void head_kernel(
        const float* __restrict__ sums, const int* __restrict__ batch,
        const float* __restrict__ hW1, const float* __restrict__ hb1,
        const float* __restrict__ hg1, const float* __restrict__ hbb1,
        const float* __restrict__ hm1, const float* __restrict__ hv1,
        const float* __restrict__ hW2, const float* __restrict__ hb2,
        const float* __restrict__ hg2, const float* __restrict__ hbb2,
        const float* __restrict__ hm2, const float* __restrict__ hv2,
        const float* __restrict__ hW3, const float* __restrict__ hb3,
        const float* __restrict__ hW4, const float* __restrict__ hb4,
        float* __restrict__ out) {
    __shared__ int se[2];
    __shared__ float pooled[64];
    __shared__ float z1[256];
    __shared__ float z2[128];
    __shared__ float z3[64];
    int g = blockIdx.x;
    int t = threadIdx.x;
    if (t < 2) {
        int target = g + t;
        int lo = 0, hi = N_NODES;
        while (lo < hi) {
            int mid = (lo + hi) >> 1;
            if (batch[mid] < target) lo = mid + 1; else hi = mid;
        }
        se[t] = lo;
    }
    __syncthreads();
    if (t < 64) {
        float cntf = (float)(se[1] - se[0]);
        cntf = cntf > 1.0f ? cntf : 1.0f;
        pooled[t] = sums[(size_t)g * 64 + t] / cntf;
    }
    __syncthreads();
    {   // layer 1: 64 -> 256, BN + relu
        float acc = hb1[t];
#pragma unroll
        for (int k = 0; k < 64; k++) acc += pooled[k] * hW1[k * 256 + t];
        acc = (acc - hm1[t]) * (1.0f / sqrtf(hv1[t] + EPS)) * hg1[t] + hbb1[t];
        z1[t] = acc > 0.0f ? acc : 0.0f;
    }
    __syncthreads();
    if (t < 128) {  // layer 2: 256 -> 128, BN + relu
        float acc = hb2[t];
#pragma unroll 8
        for (int k = 0; k < 256; k++) acc += z1[k] * hW2[k * 128 + t];
        acc = (acc - hm2[t]) * (1.0f / sqrtf(hv2[t] + EPS)) * hg2[t] + hbb2[t];
        z2[t] = acc > 0.0f ? acc : 0.0f;
    }
    __syncthreads();
    if (t < 64) {   // layer 3: 128 -> 64, relu
        float acc = hb3[t];
#pragma unroll 8
        for (int k = 0; k < 128; k++) acc += z2[k] * hW3[k * 64 + t];
        z3[t] = acc > 0.0f ? acc : 0.0f;
    }
    __syncthreads();
    if (t < 64) {   // layer 4: 64 -> 1, wave reduce
        float v = z3[t] * hW4[t];
        for (int off = 32; off > 0; off >>= 1) v += __shfl_down(v, off, 64);
        if (t == 0) out[g] = v + hb4[0];
    }
}

extern "C" void kernel_launch(void* const* d_in, const int* in_sizes, int n_in,
                              void* d_out, int out_size, void* d_ws, size_t ws_size,
                              hipStream_t stream) {
    const float* x     = (const float*)d_in[0];
    const int*   ei    = (const int*)d_in[1];   // [2, E] int32
    const int*   batch = (const int*)d_in[2];
    const float* W0 = (const float*)d_in[3];
    const float* b0 = (const float*)d_in[4];
    const float* g0 = (const float*)d_in[5];
    const float* bb0 = (const float*)d_in[6];
    const float* m0 = (const float*)d_in[7];
    const float* v0 = (const float*)d_in[8];
    const float* W1 = (const float*)d_in[9];
    const float* b1 = (const float*)d_in[10];
    const float* g1 = (const float*)d_in[11];
    const float* bb1 = (const float*)d_in[12];
    const float* m1 = (const float*)d_in[13];
    const float* v1 = (const float*)d_in[14];
    const float* hW1 = (const float*)d_in[15];
    const float* hb1 = (const float*)d_in[16];
    const float* hg1 = (const float*)d_in[17];
    const float* hbb1 = (const float*)d_in[18];
    const float* hm1 = (const float*)d_in[19];
    const float* hv1 = (const float*)d_in[20];
    const float* hW2 = (const float*)d_in[21];
    const float* hb2 = (const float*)d_in[22];
    const float* hg2 = (const float*)d_in[23];
    const float* hbb2 = (const float*)d_in[24];
    const float* hm2 = (const float*)d_in[25];
    const float* hv2 = (const float*)d_in[26];
    const float* hW3 = (const float*)d_in[27];
    const float* hb3 = (const float*)d_in[28];
    const float* hW4 = (const float*)d_in[29];
    const float* hb4 = (const float*)d_in[30];
    float* out = (float*)d_out;

    // workspace layout (16B-aligned pieces)
    __half* xwhA = (__half*)d_ws;                            // N*64 fp16 (layer-0 XW, unscaled)
    __half* xwhB = xwhA + (size_t)N_NODES * D;               // N*64 fp16 (layer-1 XW, unscaled)
    int*    cnt  = (int*)(xwhB + (size_t)N_NODES * D);       // N ints (in-degree)
    float*  sums = (float*)(cnt + N_NODES);                  // 256*64 f32 (pool partial sums)
    unsigned short* ssrc = (unsigned short*)(sums + NUM_GRAPHS * D);  // N*cap ushorts

    size_t used = (size_t)2 * N_NODES * D * 2 + (size_t)N_NODES * 4
                + (size_t)NUM_GRAPHS * D * 4;
    int cap = 64;
    if (ws_size >= used) {
        size_t avail = (ws_size - used) / ((size_t)N_NODES * 2);
        if (avail < (size_t)cap) cap = (int)avail & ~7;
    } else {
        cap = 0;
    }

    // zero cnt + sums in one fill
    hipMemsetAsync(cnt, 0, (size_t)N_NODES * 4 + (size_t)NUM_GRAPHS * D * 4, stream);

    // 1) CSR build ∥ gemm0  (independent: gemm stores unscaled fp16 table)
    build_gemm_kernel<<<SCAT_GRID + GEMM_BLOCKS, 256, 0, stream>>>(
        ei, cnt, ssrc, cap, x, W0, xwhA);

    // 2) agg0+BN+ReLU fused with gemm(W1)
    agg_gemm_kernel<<<GEMM_BLOCKS, 512, 0, stream>>>(
        xwhA, cnt, ssrc, cap, b0, g0, bb0, m0, v0, W1, xwhB, N_NODES);

    // 3) agg1+BN+ReLU fused with mean-pool partial sums
    agg_pool_kernel<<<GEMM_BLOCKS, 512, 0, stream>>>(
        xwhB, cnt, ssrc, cap, b1, g1, bb1, m1, v1, batch, sums, N_NODES);

    // 4) pooled mean + MLP head
    head_kernel<<<NUM_GRAPHS, 256, 0, stream>>>(sums, batch,
        hW1, hb1, hg1, hbb1, hm1, hv1,
        hW2, hb2, hg2, hbb2, hm2, hv2,
        hW3, hb3, hW4, hb4, out);
}

// Round 2
// 261.676 us; speedup vs baseline: 1.1317x; 1.1317x over previous
//
#include <hip/hip_runtime.h>
#include <hip/hip_bf16.h>
#include <hip/hip_fp16.h>

#define N_NODES 50000
#define N_EDGES 800000
#define NUM_GRAPHS 256
#define D 64
#define EPS 1e-5f
#define N_PART 8
#define PART_SIZE (N_NODES / N_PART)   // 6250
#define SCAT_CHUNKS 512
#define SCAT_GRID (SCAT_CHUNKS * N_PART)
#define GEMM_BLOCKS ((N_NODES + 63) / 64)   // 782
#define WP 72   // padded LDS row stride in halves (16B-aligned, conflict-breaking)

typedef _Float16 half8_t __attribute__((ext_vector_type(8)));
typedef float f32x4 __attribute__((ext_vector_type(4)));

// ---------------------------------------------------------------------------
// accumulate a 16B (8-half) chunk with weight w into two float4 accumulators
__device__ __forceinline__ void acc16(const uint4& v, float w, float4& A, float4& B) {
    const __half2* hp = (const __half2*)&v;
    float2 q0 = __half22float2(hp[0]), q1 = __half22float2(hp[1]);
    float2 q2 = __half22float2(hp[2]), q3 = __half22float2(hp[3]);
    A.x += w * q0.x; A.y += w * q0.y; A.z += w * q1.x; A.w += w * q1.y;
    B.x += w * q2.x; B.y += w * q2.y; B.z += w * q3.x; B.w += w * q3.y;
}

// ---------------------------------------------------------------------------
// 1) FUSED: slotted-CSR build (XCD-partitioned, int4 col scan) running
//    CONCURRENTLY with gemm0 (Yh = X@W0, fp16, UNSCALED — dinv applied by
//    scale_kernel afterwards, so gemm does not depend on cnt).
__global__ __launch_bounds__(256) void build_gemm_kernel(
        const int* __restrict__ ei, int* __restrict__ cnt,
        unsigned short* __restrict__ ssrc, int cap,
        const float* __restrict__ X, const float* __restrict__ W,
        __half* __restrict__ Yh) {
    __shared__ _Float16 Xs[64 * WP];   // [row][k]
    __shared__ _Float16 Wt[64 * WP];   // [n][k]
    if (blockIdx.x < SCAT_GRID) {
        // ---- scatter part (blockIdx&7 -> XCD affinity on dst partition) ----
        int p     = blockIdx.x & (N_PART - 1);
        int chunk = blockIdx.x >> 3;
        const int per = (((N_EDGES + SCAT_CHUNKS - 1) / SCAT_CHUNKS) + 3) & ~3;  // 1564
        int lo = chunk * per;
        int hi = lo + per; if (hi > N_EDGES) hi = N_EDGES;
        for (int e4 = lo + (int)threadIdx.x * 4; e4 < hi; e4 += 1024) {
            int4 c4 = *(const int4*)&ei[N_EDGES + e4];   // 16B-aligned: lo%4==0
            const int* cc = (const int*)&c4;
#pragma unroll
            for (int k = 0; k < 4; k++) {
                int e = e4 + k;
                if (e < hi) {
                    int c = cc[k];
                    if (c / PART_SIZE == p) {
                        int r = ei[e];
                        int pos = atomicAdd(&cnt[c], 1);
                        if (pos < cap) ssrc[(size_t)c * cap + pos] = (unsigned short)r;
                    }
                }
            }
        }
        return;
    }
    // ---- gemm0 part ----
    int tid  = threadIdx.x;
    int base = (blockIdx.x - SCAT_GRID) * 64;
    for (int i = tid; i < 4096; i += 256) {       // stage W^T fp16
        int k = i >> 6, n = i & 63;
        Wt[n * WP + k] = (_Float16)W[i];
    }
    for (int i = tid; i < 1024; i += 256) {       // stage X rows fp16
        int r = i >> 4, c4 = (i & 15) * 4;
        float4 xv = (base + r < N_NODES)
            ? ((const float4*)X)[(size_t)(base + r) * 16 + (i & 15)]
            : make_float4(0.f, 0.f, 0.f, 0.f);
        _Float16* dst = &Xs[r * WP + c4];
        dst[0] = (_Float16)xv.x; dst[1] = (_Float16)xv.y;
        dst[2] = (_Float16)xv.z; dst[3] = (_Float16)xv.w;
    }
    __syncthreads();
    int wave  = tid >> 6;
    int lane  = tid & 63;
    int m     = lane & 15;
    int q     = lane >> 4;
    int row16 = wave * 16;
    half8_t a0 = *(const half8_t*)&Xs[(row16 + m) * WP + q * 8];
    half8_t a1 = *(const half8_t*)&Xs[(row16 + m) * WP + 32 + q * 8];
    f32x4 acc[4];
#pragma unroll
    for (int ct = 0; ct < 4; ct++) {
        half8_t b0 = *(const half8_t*)&Wt[(ct * 16 + m) * WP + q * 8];
        half8_t b1 = *(const half8_t*)&Wt[(ct * 16 + m) * WP + 32 + q * 8];
        f32x4 c = {0.f, 0.f, 0.f, 0.f};
        c = __builtin_amdgcn_mfma_f32_16x16x32_f16(a0, b0, c, 0, 0, 0);
        c = __builtin_amdgcn_mfma_f32_16x16x32_f16(a1, b1, c, 0, 0, 0);
        acc[ct] = c;
    }
#pragma unroll
    for (int ct = 0; ct < 4; ct++) {
#pragma unroll
        for (int reg = 0; reg < 4; reg++) {
            int row = base + row16 + q * 4 + reg;
            if (row < N_NODES)
                Yh[(size_t)row * 64 + ct * 16 + m] = (__half)acc[ct][reg];
        }
    }
}

// ---------------------------------------------------------------------------
// 2) tiny BW-bound pass: xwh[row] *= rsqrt(cnt[row]+1)   (one uint4 / thread)
__global__ __launch_bounds__(256) void scale_kernel(__half* __restrict__ xwh,
                                                    const int* __restrict__ cnt,
                                                    int N) {
    int i = blockIdx.x * 256 + threadIdx.x;   // chunk index over N*8 uint4s
    if (i >= N * 8) return;
    int row = i >> 3;
    float w = rsqrtf((float)cnt[row] + 1.0f);
    uint4 v = ((const uint4*)xwh)[i];
    __half2* hp = (__half2*)&v;
#pragma unroll
    for (int j = 0; j < 4; j++) {
        float2 q = __half22float2(hp[j]);
        hp[j] = __floats2half2_rn(q.x * w, q.y * w);
    }
    ((uint4*)xwh)[i] = v;
}

// ---------------------------------------------------------------------------
// 3) aggregation + self-loop + gcn bias + BN + ReLU.  Wave-per-node (50000
//    waves).  Slot indices loaded ONCE (2B/lane coalesced), broadcast per
//    iteration via __shfl; gathers software-pipelined 1-deep.  Table is
//    pre-scaled by dinv[src], epilogue applies dinv[dst].
__global__ __launch_bounds__(256) void agg_bn_kernel(
        const __half* __restrict__ xwh, const int* __restrict__ cnt,
        const unsigned short* __restrict__ ssrc, int cap,
        const float* __restrict__ b, const float* __restrict__ g,
        const float* __restrict__ bb, const float* __restrict__ m,
        const float* __restrict__ var,
        float* __restrict__ out, int N) {
    int wave = (blockIdx.x * blockDim.x + threadIdx.x) >> 6;
    int lane = threadIdx.x & 63;
    if (wave >= N) return;
    int c   = wave;
    int sub = lane >> 3;        // which of 8 concurrent edges
    int f2  = lane & 7;         // feature group: feats 8*f2 .. 8*f2+7
    const uint4* xw8 = (const uint4*)xwh;
    int n = cnt[c];
    if (n > cap) n = cap;
    float dc = rsqrtf((float)n + 1.0f);
    size_t sbase = (size_t)c * cap;
    // one coalesced load of the whole slot list (slot = lane)
    int idx = (lane < cap) ? (int)ssrc[sbase + lane] : 0;
    // self-loop gather issued early (sub==0 lanes cover all 8 chunks)
    uint4 vself = make_uint4(0u, 0u, 0u, 0u);
    if (sub == 0) vself = xw8[(size_t)c * 8 + f2];
    int t = (n + 7) >> 3;
    float4 accA = make_float4(0.f, 0.f, 0.f, 0.f);
    float4 accB = accA;
    uint4 vc = make_uint4(0u, 0u, 0u, 0u);
    float wc = 0.0f;
    if (t > 0) {   // prologue: issue gather for slots sub
        int r0 = __shfl(idx, sub, 64);
        wc = (sub < n) ? 1.0f : 0.0f;
        if (sub >= n) r0 = c;           // redirect invalid to cache-hot row
        vc = xw8[(size_t)r0 * 8 + f2];
    }
    for (int k = 1; k < t; k++) {   // 1-deep pipelined steady state
        int s  = k * 8 + sub;
        int r1 = __shfl(idx, s, 64);
        float wn = (s < n) ? 1.0f : 0.0f;
        if (s >= n) r1 = c;
        uint4 vn = xw8[(size_t)r1 * 8 + f2];   // issue BEFORE consuming vc
        acc16(vc, wc, accA, accB);
        vc = vn; wc = wn;
    }
    if (t > 0) acc16(vc, wc, accA, accB);
    if (sub == 0) acc16(vself, 1.0f, accA, accB);   // self term (table pre-scaled)
#pragma unroll
    for (int off = 8; off < 64; off <<= 1) {
        accA.x += __shfl_xor(accA.x, off, 64); accA.y += __shfl_xor(accA.y, off, 64);
        accA.z += __shfl_xor(accA.z, off, 64); accA.w += __shfl_xor(accA.w, off, 64);
        accB.x += __shfl_xor(accB.x, off, 64); accB.y += __shfl_xor(accB.y, off, 64);
        accB.z += __shfl_xor(accB.z, off, 64); accB.w += __shfl_xor(accB.w, off, 64);
    }
    if (sub < 2) {   // BN+ReLU epilogue split across 2 subs
        int i4 = 2 * f2 + sub;
        float4 acc = sub ? accB : accA;
        float4 b4  = ((const float4*)b)[i4];
        float4 m4  = ((const float4*)m)[i4];
        float4 v4_ = ((const float4*)var)[i4];
        float4 g4  = ((const float4*)g)[i4];
        float4 bb4 = ((const float4*)bb)[i4];
        float4 h;
        h.x = (acc.x * dc + b4.x - m4.x) * (1.0f / sqrtf(v4_.x + EPS)) * g4.x + bb4.x;
        h.y = (acc.y * dc + b4.y - m4.y) * (1.0f / sqrtf(v4_.y + EPS)) * g4.y + bb4.y;
        h.z = (acc.z * dc + b4.z - m4.z) * (1.0f / sqrtf(v4_.z + EPS)) * g4.z + bb4.z;
        h.w = (acc.w * dc + b4.w - m4.w) * (1.0f / sqrtf(v4_.w + EPS)) * g4.w + bb4.w;
        h.x = h.x > 0.f ? h.x : 0.f;
        h.y = h.y > 0.f ? h.y : 0.f;
        h.z = h.z > 0.f ? h.z : 0.f;
        h.w = h.w > 0.f ? h.w : 0.f;
        ((float4*)out)[(size_t)c * 16 + i4] = h;
    }
}

// ---------------------------------------------------------------------------
// 4) MFMA GEMM for layer 1: Yh[N,64](fp16) = dinv[row] * (H[N,64] @ W[64,64]).
//    cnt is final here, so dinv is fused in the epilogue (pre-scaled table).
__global__ __launch_bounds__(256) void gemm64_kernel(const float* __restrict__ X,
                                                     const float* __restrict__ W,
                                                     const int* __restrict__ cnt,
                                                     __half* __restrict__ Yh, int N) {
    __shared__ _Float16 Xs[64 * WP];   // [row][k]
    __shared__ _Float16 Wt[64 * WP];   // [n][k]
    int tid  = threadIdx.x;
    int base = blockIdx.x * 64;
    for (int i = tid; i < 4096; i += 256) {
        int k = i >> 6, n = i & 63;
        Wt[n * WP + k] = (_Float16)W[i];
    }
    for (int i = tid; i < 1024; i += 256) {
        int r = i >> 4, c4 = (i & 15) * 4;
        float4 xv = (base + r < N)
            ? ((const float4*)X)[(size_t)(base + r) * 16 + (i & 15)]
            : make_float4(0.f, 0.f, 0.f, 0.f);
        _Float16* dst = &Xs[r * WP + c4];
        dst[0] = (_Float16)xv.x; dst[1] = (_Float16)xv.y;
        dst[2] = (_Float16)xv.z; dst[3] = (_Float16)xv.w;
    }
    __syncthreads();
    int wave  = tid >> 6;
    int lane  = tid & 63;
    int m     = lane & 15;
    int q     = lane >> 4;
    int row16 = wave * 16;
    half8_t a0 = *(const half8_t*)&Xs[(row16 + m) * WP + q * 8];
    half8_t a1 = *(const half8_t*)&Xs[(row16 + m) * WP + 32 + q * 8];
    f32x4 acc[4];
#pragma unroll
    for (int ct = 0; ct < 4; ct++) {
        half8_t b0 = *(const half8_t*)&Wt[(ct * 16 + m) * WP + q * 8];
        half8_t b1 = *(const half8_t*)&Wt[(ct * 16 + m) * WP + 32 + q * 8];
        f32x4 c = {0.f, 0.f, 0.f, 0.f};
        c = __builtin_amdgcn_mfma_f32_16x16x32_f16(a0, b0, c, 0, 0, 0);
        c = __builtin_amdgcn_mfma_f32_16x16x32_f16(a1, b1, c, 0, 0, 0);
        acc[ct] = c;
    }
    int   rows[4];
    float ws[4];
#pragma unroll
    for (int reg = 0; reg < 4; reg++) {
        rows[reg] = base + row16 + q * 4 + reg;
        ws[reg] = (rows[reg] < N) ? rsqrtf((float)cnt[rows[reg]] + 1.0f) : 0.0f;
    }
#pragma unroll
    for (int ct = 0; ct < 4; ct++) {
#pragma unroll
        for (int reg = 0; reg < 4; reg++) {
            if (rows[reg] < N)
                Yh[(size_t)rows[reg] * 64 + ct * 16 + m] =
                    (__half)(ws[reg] * acc[ct][reg]);
        }
    }
}

// ---------------------------------------------------------------------------
// 5) fused mean-pool (via sorted-batch binary search) + full MLP head.
__global__ __launch_bounds__(256) void pool_head_kernel(
        const float* __restrict__ h, const int* __restrict__ batch,
        const float* __restrict__ hW1, const float* __restrict__ hb1,
        const float* __restrict__ hg1, const float* __restrict__ hbb1,
        const float* __restrict__ hm1, const float* __restrict__ hv1,
        const float* __restrict__ hW2, const float* __restrict__ hb2,
        const float* __restrict__ hg2, const float* __restrict__ hbb2,
        const float* __restrict__ hm2, const float* __restrict__ hv2,
        const float* __restrict__ hW3, const float* __restrict__ hb3,
        const float* __restrict__ hW4, const float* __restrict__ hb4,
        float* __restrict__ out) {
    __shared__ int se[2];
    __shared__ float red[256];
    __shared__ float pooled[64];
    __shared__ float z1[256];
    __shared__ float z2[128];
    __shared__ float z3[64];
    int g = blockIdx.x;
    int t = threadIdx.x;
    if (t < 2) {
        int target = g + t;
        int lo = 0, hi = N_NODES;
        while (lo < hi) {
            int mid = (lo + hi) >> 1;
            if (batch[mid] < target) lo = mid + 1; else hi = mid;
        }
        se[t] = lo;
    }
    __syncthreads();
    int start = se[0], end = se[1];
    {   // mean pool: 4 row-groups x 64 features
        int f = t & 63, rg = t >> 6;
        float part = 0.0f;
        for (int r = start + rg; r < end; r += 4) part += h[(size_t)r * 64 + f];
        red[t] = part;
        __syncthreads();
        if (t < 64) {
            float s = red[t] + red[t + 64] + red[t + 128] + red[t + 192];
            float cnt = (float)(end - start);
            cnt = cnt > 1.0f ? cnt : 1.0f;
            pooled[t] = s / cnt;
        }
    }
    __syncthreads();
    {   // layer 1: 64 -> 256, BN + relu
        float acc = hb1[t];
#pragma unroll
        for (int k = 0; k < 64; k++) acc += pooled[k] * hW1[k * 256 + t];
        acc = (acc - hm1[t]) * (1.0f / sqrtf(hv1[t] + EPS)) * hg1[t] + hbb1[t];
        z1[t] = acc > 0.0f ? acc : 0.0f;
    }
    __syncthreads();
    if (t < 128) {  // layer 2: 256 -> 128, BN + relu
        float acc = hb2[t];
#pragma unroll 8
        for (int k = 0; k < 256; k++) acc += z1[k] * hW2[k * 128 + t];
        acc = (acc - hm2[t]) * (1.0f / sqrtf(hv2[t] + EPS)) * hg2[t] + hbb2[t];
        z2[t] = acc > 0.0f ? acc : 0.0f;
    }
    __syncthreads();
    if (t < 64) {   // layer 3: 128 -> 64, relu
        float acc = hb3[t];
#pragma unroll 8
        for (int k = 0; k < 128; k++) acc += z2[k] * hW3[k * 64 + t];
        z3[t] = acc > 0.0f ? acc : 0.0f;
    }
    __syncthreads();
    if (t < 64) {   // layer 4: 64 -> 1, wave reduce
        float v = z3[t] * hW4[t];
        for (int off = 32; off > 0; off >>= 1) v += __shfl_down(v, off, 64);
        if (t == 0) out[g] = v + hb4[0];
    }
}

extern "C" void kernel_launch(void* const* d_in, const int* in_sizes, int n_in,
                              void* d_out, int out_size, void* d_ws, size_t ws_size,
                              hipStream_t stream) {
    const float* x     = (const float*)d_in[0];
    const int*   ei    = (const int*)d_in[1];   // [2, E] int32
    const int*   batch = (const int*)d_in[2];
    const float* W0 = (const float*)d_in[3];
    const float* b0 = (const float*)d_in[4];
    const float* g0 = (const float*)d_in[5];
    const float* bb0 = (const float*)d_in[6];
    const float* m0 = (const float*)d_in[7];
    const float* v0 = (const float*)d_in[8];
    const float* W1 = (const float*)d_in[9];
    const float* b1 = (const float*)d_in[10];
    const float* g1 = (const float*)d_in[11];
    const float* bb1 = (const float*)d_in[12];
    const float* m1 = (const float*)d_in[13];
    const float* v1 = (const float*)d_in[14];
    const float* hW1 = (const float*)d_in[15];
    const float* hb1 = (const float*)d_in[16];
    const float* hg1 = (const float*)d_in[17];
    const float* hbb1 = (const float*)d_in[18];
    const float* hm1 = (const float*)d_in[19];
    const float* hv1 = (const float*)d_in[20];
    const float* hW2 = (const float*)d_in[21];
    const float* hb2 = (const float*)d_in[22];
    const float* hg2 = (const float*)d_in[23];
    const float* hbb2 = (const float*)d_in[24];
    const float* hm2 = (const float*)d_in[25];
    const float* hv2 = (const float*)d_in[26];
    const float* hW3 = (const float*)d_in[27];
    const float* hb3 = (const float*)d_in[28];
    const float* hW4 = (const float*)d_in[29];
    const float* hb4 = (const float*)d_in[30];
    float* out = (float*)d_out;

    // workspace layout (16B-aligned pieces)
    __half* xwhA = (__half*)d_ws;                            // N*64 fp16 (layer-0 table)
    __half* xwhB = xwhA + (size_t)N_NODES * D;               // N*64 fp16 (layer-1 table)
    float*  bufB = (float*)(xwhB + (size_t)N_NODES * D);     // N*64 f32 (node features)
    int*    cnt  = (int*)(bufB + (size_t)N_NODES * D);       // N ints (in-degree)
    unsigned short* ssrc = (unsigned short*)(cnt + N_NODES); // N*cap ushorts

    size_t used = (size_t)2 * N_NODES * D * 2 + (size_t)N_NODES * D * 4
                + (size_t)N_NODES * 4;
    int cap = 64;
    if (ws_size >= used) {
        size_t avail = (ws_size - used) / ((size_t)N_NODES * 2);
        if (avail < (size_t)cap) cap = (int)avail & ~7;
    } else {
        cap = 0;
    }

    const int NT = 256;
    hipMemsetAsync(cnt, 0, (size_t)N_NODES * 4, stream);

    // 1) CSR build ∥ gemm0 (unscaled fp16 table — no cnt dependency)
    build_gemm_kernel<<<SCAT_GRID + GEMM_BLOCKS, NT, 0, stream>>>(
        ei, cnt, ssrc, cap, x, W0, xwhA);

    // 2) apply dinv[row] to the layer-0 table (tiny BW-bound pass)
    scale_kernel<<<(N_NODES * 8 + NT - 1) / NT, NT, 0, stream>>>(xwhA, cnt, N_NODES);

    // 3) agg0 + BN + ReLU (wave-per-node, pipelined gathers)
    agg_bn_kernel<<<(N_NODES * 64) / NT, NT, 0, stream>>>(
        xwhA, cnt, ssrc, cap, b0, g0, bb0, m0, v0, bufB, N_NODES);

    // 4) gemm1 with fused dinv pre-scale (cnt final)
    gemm64_kernel<<<GEMM_BLOCKS, NT, 0, stream>>>(bufB, W1, cnt, xwhB, N_NODES);

    // 5) agg1 + BN + ReLU
    agg_bn_kernel<<<(N_NODES * 64) / NT, NT, 0, stream>>>(
        xwhB, cnt, ssrc, cap, b1, g1, bb1, m1, v1, bufB, N_NODES);

    // 6) mean pool + MLP head (fused)
    pool_head_kernel<<<NUM_GRAPHS, NT, 0, stream>>>(bufB, batch,
        hW1, hb1, hg1, hbb1, hm1, hv1,
        hW2, hb2, hg2, hbb2, hm2, hv2,
        hW3, hb3, hW4, hb4, out);
}

// Round 4
// 258.186 us; speedup vs baseline: 1.1470x; 1.0135x over previous
//
#include <hip/hip_runtime.h>
#include <hip/hip_bf16.h>
#include <hip/hip_fp16.h>

#define N_NODES 50000
#define N_EDGES 800000
#define NUM_GRAPHS 256
#define D 64
#define EPS 1e-5f
#define N_PART 8
#define PART_SIZE (N_NODES / N_PART)   // 6250
#define SCAT_CHUNKS 512
#define SCAT_GRID (SCAT_CHUNKS * N_PART)
#define GEMM_BLOCKS ((N_NODES + 63) / 64)   // 782
#define WP 72   // padded LDS row stride in halves (16B-aligned, conflict-breaking)

typedef _Float16 half8_t __attribute__((ext_vector_type(8)));
typedef _Float16 half4_t __attribute__((ext_vector_type(4)));
typedef float f32x4 __attribute__((ext_vector_type(4)));

// ---------------------------------------------------------------------------
// accumulate a 16B (8-half) chunk with weight w into two float4 accumulators
__device__ __forceinline__ void acc16(const uint4& v, float w, float4& A, float4& B) {
    const __half2* hp = (const __half2*)&v;
    float2 q0 = __half22float2(hp[0]), q1 = __half22float2(hp[1]);
    float2 q2 = __half22float2(hp[2]), q3 = __half22float2(hp[3]);
    A.x += w * q0.x; A.y += w * q0.y; A.z += w * q1.x; A.w += w * q1.y;
    B.x += w * q2.x; B.y += w * q2.y; B.z += w * q3.x; B.w += w * q3.y;
}

// ---------------------------------------------------------------------------
// 1) FUSED: gemm0 (blocks 0..781) ∥ slotted-CSR build (blocks 782..).
//    GEMM blocks FIRST so the first co-resident generation mixes streaming/
//    MFMA work with atomic-latency-bound scatter work.  X is loaded
//    non-temporally (read-once) to stop evicting partial ssrc cachelines.
//    Table is UNSCALED fp16 — dinv applied per-edge in agg (no cnt dep).
__global__ __launch_bounds__(256) void build_gemm_kernel(
        const int* __restrict__ ei, int* __restrict__ cnt,
        unsigned short* __restrict__ ssrc, int cap,
        const float* __restrict__ X, const float* __restrict__ W,
        __half* __restrict__ Yh) {
    __shared__ _Float16 Xs[64 * WP];   // [row][k]
    __shared__ _Float16 Wt[64 * WP];   // [n][k]
    if (blockIdx.x >= GEMM_BLOCKS) {
        // ---- scatter part (blockIdx&7 -> XCD affinity on dst partition) ----
        int scat  = blockIdx.x - GEMM_BLOCKS;
        int p     = blockIdx.x & (N_PART - 1);
        int chunk = scat >> 3;
        const int per = (((N_EDGES + SCAT_CHUNKS - 1) / SCAT_CHUNKS) + 3) & ~3;  // 1564
        int lo = chunk * per;
        int hi = lo + per; if (hi > N_EDGES) hi = N_EDGES;
        for (int e4 = lo + (int)threadIdx.x * 4; e4 < hi; e4 += 1024) {
            int4 c4 = *(const int4*)&ei[N_EDGES + e4];   // 16B-aligned: lo%4==0
            const int* cc = (const int*)&c4;
#pragma unroll
            for (int k = 0; k < 4; k++) {
                int e = e4 + k;
                if (e < hi) {
                    int c = cc[k];
                    if (c / PART_SIZE == p) {
                        int r = ei[e];
                        int pos = atomicAdd(&cnt[c], 1);
                        if (pos < cap) ssrc[(size_t)c * cap + pos] = (unsigned short)r;
                    }
                }
            }
        }
        return;
    }
    // ---- gemm0 part ----
    int tid  = threadIdx.x;
    int base = blockIdx.x * 64;
    for (int i = tid; i < 4096; i += 256) {       // stage W^T fp16
        int k = i >> 6, n = i & 63;
        Wt[n * WP + k] = (_Float16)W[i];
    }
    for (int i = tid; i < 1024; i += 256) {       // stage X rows fp16 (NT loads)
        int r = i >> 4, c4 = (i & 15) * 4;
        f32x4 xv;
        if (base + r < N_NODES) {
            xv = __builtin_nontemporal_load(
                     &((const f32x4*)X)[(size_t)(base + r) * 16 + (i & 15)]);
        } else {
            xv = (f32x4){0.f, 0.f, 0.f, 0.f};
        }
        _Float16* dst = &Xs[r * WP + c4];
        dst[0] = (_Float16)xv.x; dst[1] = (_Float16)xv.y;
        dst[2] = (_Float16)xv.z; dst[3] = (_Float16)xv.w;
    }
    __syncthreads();
    int wave  = tid >> 6;
    int lane  = tid & 63;
    int m     = lane & 15;
    int q     = lane >> 4;
    int row16 = wave * 16;
    half8_t a0 = *(const half8_t*)&Xs[(row16 + m) * WP + q * 8];
    half8_t a1 = *(const half8_t*)&Xs[(row16 + m) * WP + 32 + q * 8];
    f32x4 acc[4];
#pragma unroll
    for (int ct = 0; ct < 4; ct++) {
        half8_t b0 = *(const half8_t*)&Wt[(ct * 16 + m) * WP + q * 8];
        half8_t b1 = *(const half8_t*)&Wt[(ct * 16 + m) * WP + 32 + q * 8];
        f32x4 c = {0.f, 0.f, 0.f, 0.f};
        c = __builtin_amdgcn_mfma_f32_16x16x32_f16(a0, b0, c, 0, 0, 0);
        c = __builtin_amdgcn_mfma_f32_16x16x32_f16(a1, b1, c, 0, 0, 0);
        acc[ct] = c;
    }
#pragma unroll
    for (int ct = 0; ct < 4; ct++) {
#pragma unroll
        for (int reg = 0; reg < 4; reg++) {
            int row = base + row16 + q * 4 + reg;
            if (row < N_NODES)
                Yh[(size_t)row * 64 + ct * 16 + m] = (__half)acc[ct][reg];
        }
    }
}

// ---------------------------------------------------------------------------
// 2) aggregation + self-loop + gcn bias + BN + ReLU.  Wave-per-node.
//    Table is UNSCALED; per-edge weight dinv[r] = rsqrt(cnt[r]+1) with the
//    cnt gather issued alongside the row gather (independent loads).
//    2-deep software pipeline: two row-gathers + two cnt loads in flight.
//    OUTF16: write h as fp16 (consumed by gemm1h) vs f32 (consumed by head).
template<bool OUTF16>
__global__ __launch_bounds__(256) void agg_bn_kernel(
        const __half* __restrict__ xwh, const int* __restrict__ cnt,
        const unsigned short* __restrict__ ssrc, int cap,
        const float* __restrict__ b, const float* __restrict__ g,
        const float* __restrict__ bb, const float* __restrict__ m,
        const float* __restrict__ var,
        void* __restrict__ out, int N) {
    int wave = (blockIdx.x * blockDim.x + threadIdx.x) >> 6;
    int lane = threadIdx.x & 63;
    if (wave >= N) return;
    int c   = wave;
    int sub = lane >> 3;        // which of 8 concurrent edges
    int f2  = lane & 7;         // feature group: feats 8*f2 .. 8*f2+7
    const uint4* xw8 = (const uint4*)xwh;
    int n = cnt[c];
    if (n > cap) n = cap;
    float dc = rsqrtf((float)n + 1.0f);
    size_t sbase = (size_t)c * cap;
    // one coalesced load of the whole slot list (slot = lane)
    int idx = (lane < cap) ? (int)ssrc[sbase + lane] : 0;
    // self-loop gather issued early (sub==0 lanes cover all 8 chunks)
    uint4 vself = make_uint4(0u, 0u, 0u, 0u);
    if (sub == 0) vself = xw8[(size_t)c * 8 + f2];
    int t = (n + 7) >> 3;
    float4 accA = make_float4(0.f, 0.f, 0.f, 0.f);
    float4 accB = accA;

    uint4 v0 = make_uint4(0u,0u,0u,0u), v1 = v0;
    int   cv0 = -1, cv1 = -1;
    auto issue = [&](int k, uint4& v, int& cv) {
        int s = k * 8 + sub;
        int sc = (s < n) ? s : 0;            // shfl executed by ALL lanes
        int r  = __shfl(idx, sc, 64);
        if (s >= n) r = c;                   // redirect invalid to cache-hot row
        cv = (s < n) ? cnt[r] : -1;          // cnt gather ∥ row gather
        v  = xw8[(size_t)r * 8 + f2];
    };
    auto consume = [&](const uint4& v, int cv) {
        if (cv >= 0) acc16(v, rsqrtf((float)cv + 1.0f), accA, accB);
    };
    if (t > 0) issue(0, v0, cv0);
    if (t > 1) issue(1, v1, cv1);
    for (int k = 0; k < t; k++) {
        consume(v0, cv0);
        v0 = v1; cv0 = cv1;
        if (k + 2 < t) issue(k + 2, v1, cv1); else cv1 = -1;
    }
    if (sub == 0) acc16(vself, dc, accA, accB);   // self term: dc (epilogue adds 2nd dc)
#pragma unroll
    for (int off = 8; off < 64; off <<= 1) {
        accA.x += __shfl_xor(accA.x, off, 64); accA.y += __shfl_xor(accA.y, off, 64);
        accA.z += __shfl_xor(accA.z, off, 64); accA.w += __shfl_xor(accA.w, off, 64);
        accB.x += __shfl_xor(accB.x, off, 64); accB.y += __shfl_xor(accB.y, off, 64);
        accB.z += __shfl_xor(accB.z, off, 64); accB.w += __shfl_xor(accB.w, off, 64);
    }
    if (sub < 2) {   // BN+ReLU epilogue split across 2 subs
        int i4 = 2 * f2 + sub;
        float4 acc = sub ? accB : accA;
        float4 b4  = ((const float4*)b)[i4];
        float4 m4  = ((const float4*)m)[i4];
        float4 v4_ = ((const float4*)var)[i4];
        float4 g4  = ((const float4*)g)[i4];
        float4 bb4 = ((const float4*)bb)[i4];
        float4 h;
        h.x = (acc.x * dc + b4.x - m4.x) * (1.0f / sqrtf(v4_.x + EPS)) * g4.x + bb4.x;
        h.y = (acc.y * dc + b4.y - m4.y) * (1.0f / sqrtf(v4_.y + EPS)) * g4.y + bb4.y;
        h.z = (acc.z * dc + b4.z - m4.z) * (1.0f / sqrtf(v4_.z + EPS)) * g4.z + bb4.z;
        h.w = (acc.w * dc + b4.w - m4.w) * (1.0f / sqrtf(v4_.w + EPS)) * g4.w + bb4.w;
        h.x = h.x > 0.f ? h.x : 0.f;
        h.y = h.y > 0.f ? h.y : 0.f;
        h.z = h.z > 0.f ? h.z : 0.f;
        h.w = h.w > 0.f ? h.w : 0.f;
        if (OUTF16) {
            half4_t hv = {(_Float16)h.x, (_Float16)h.y, (_Float16)h.z, (_Float16)h.w};
            *(half4_t*)((__half*)out + (size_t)c * 64 + i4 * 4) = hv;
        } else {
            ((float4*)out)[(size_t)c * 16 + i4] = h;
        }
    }
}

// ---------------------------------------------------------------------------
// 3) MFMA GEMM, fp16 input: Yh[N,64] = Xh[N,64] @ W[64,64]  (plain, unscaled)
__global__ __launch_bounds__(256) void gemm64h_kernel(const __half* __restrict__ Xh,
                                                      const float* __restrict__ W,
                                                      __half* __restrict__ Yh, int N) {
    __shared__ _Float16 Xs[64 * WP];   // [row][k]
    __shared__ _Float16 Wt[64 * WP];   // [n][k]
    int tid  = threadIdx.x;
    int base = blockIdx.x * 64;
    for (int i = tid; i < 4096; i += 256) {
        int k = i >> 6, n = i & 63;
        Wt[n * WP + k] = (_Float16)W[i];
    }
    for (int i = tid; i < 512; i += 256) {   // 64 rows x 8 16B-chunks
        int r = i >> 3, c8 = (i & 7) * 8;
        uint4 v = (base + r < N)
            ? ((const uint4*)Xh)[(size_t)(base + r) * 8 + (i & 7)]
            : make_uint4(0u, 0u, 0u, 0u);
        *(uint4*)&Xs[r * WP + c8] = v;
    }
    __syncthreads();
    int wave  = tid >> 6;
    int lane  = tid & 63;
    int m     = lane & 15;
    int q     = lane >> 4;
    int row16 = wave * 16;
    half8_t a0 = *(const half8_t*)&Xs[(row16 + m) * WP + q * 8];
    half8_t a1 = *(const half8_t*)&Xs[(row16 + m) * WP + 32 + q * 8];
    f32x4 acc[4];
#pragma unroll
    for (int ct = 0; ct < 4; ct++) {
        half8_t b0 = *(const half8_t*)&Wt[(ct * 16 + m) * WP + q * 8];
        half8_t b1 = *(const half8_t*)&Wt[(ct * 16 + m) * WP + 32 + q * 8];
        f32x4 c = {0.f, 0.f, 0.f, 0.f};
        c = __builtin_amdgcn_mfma_f32_16x16x32_f16(a0, b0, c, 0, 0, 0);
        c = __builtin_amdgcn_mfma_f32_16x16x32_f16(a1, b1, c, 0, 0, 0);
        acc[ct] = c;
    }
#pragma unroll
    for (int ct = 0; ct < 4; ct++) {
#pragma unroll
        for (int reg = 0; reg < 4; reg++) {
            int row = base + row16 + q * 4 + reg;
            if (row < N)
                Yh[(size_t)row * 64 + ct * 16 + m] = (__half)acc[ct][reg];
        }
    }
}

// ---------------------------------------------------------------------------
// 4) fused mean-pool (via sorted-batch binary search) + full MLP head.
__global__ __launch_bounds__(256) void pool_head_kernel(
        const float* __restrict__ h, const int* __restrict__ batch,
        const float* __restrict__ hW1, const float* __restrict__ hb1,
        const float* __restrict__ hg1, const float* __restrict__ hbb1,
        const float* __restrict__ hm1, const float* __restrict__ hv1,
        const float* __restrict__ hW2, const float* __restrict__ hb2,
        const float* __restrict__ hg2, const float* __restrict__ hbb2,
        const float* __restrict__ hm2, const float* __restrict__ hv2,
        const float* __restrict__ hW3, const float* __restrict__ hb3,
        const float* __restrict__ hW4, const float* __restrict__ hb4,
        float* __restrict__ out) {
    __shared__ int se[2];
    __shared__ float red[256];
    __shared__ float pooled[64];
    __shared__ float z1[256];
    __shared__ float z2[128];
    __shared__ float z3[64];
    int g = blockIdx.x;
    int t = threadIdx.x;
    if (t < 2) {
        int target = g + t;
        int lo = 0, hi = N_NODES;
        while (lo < hi) {
            int mid = (lo + hi) >> 1;
            if (batch[mid] < target) lo = mid + 1; else hi = mid;
        }
        se[t] = lo;
    }
    __syncthreads();
    int start = se[0], end = se[1];
    {   // mean pool: 4 row-groups x 64 features
        int f = t & 63, rg = t >> 6;
        float part = 0.0f;
        for (int r = start + rg; r < end; r += 4) part += h[(size_t)r * 64 + f];
        red[t] = part;
        __syncthreads();
        if (t < 64) {
            float s = red[t] + red[t + 64] + red[t + 128] + red[t + 192];
            float cnt = (float)(end - start);
            cnt = cnt > 1.0f ? cnt : 1.0f;
            pooled[t] = s / cnt;
        }
    }
    __syncthreads();
    {   // layer 1: 64 -> 256, BN + relu
        float acc = hb1[t];
#pragma unroll
        for (int k = 0; k < 64; k++) acc += pooled[k] * hW1[k * 256 + t];
        acc = (acc - hm1[t]) * (1.0f / sqrtf(hv1[t] + EPS)) * hg1[t] + hbb1[t];
        z1[t] = acc > 0.0f ? acc : 0.0f;
    }
    __syncthreads();
    if (t < 128) {  // layer 2: 256 -> 128, BN + relu
        float acc = hb2[t];
#pragma unroll 8
        for (int k = 0; k < 256; k++) acc += z1[k] * hW2[k * 128 + t];
        acc = (acc - hm2[t]) * (1.0f / sqrtf(hv2[t] + EPS)) * hg2[t] + hbb2[t];
        z2[t] = acc > 0.0f ? acc : 0.0f;
    }
    __syncthreads();
    if (t < 64) {   // layer 3: 128 -> 64, relu
        float acc = hb3[t];
#pragma unroll 8
        for (int k = 0; k < 128; k++) acc += z2[k] * hW3[k * 64 + t];
        z3[t] = acc > 0.0f ? acc : 0.0f;
    }
    __syncthreads();
    if (t < 64) {   // layer 4: 64 -> 1, wave reduce
        float v = z3[t] * hW4[t];
        for (int off = 32; off > 0; off >>= 1) v += __shfl_down(v, off, 64);
        if (t == 0) out[g] = v + hb4[0];
    }
}

extern "C" void kernel_launch(void* const* d_in, const int* in_sizes, int n_in,
                              void* d_out, int out_size, void* d_ws, size_t ws_size,
                              hipStream_t stream) {
    const float* x     = (const float*)d_in[0];
    const int*   ei    = (const int*)d_in[1];   // [2, E] int32
    const int*   batch = (const int*)d_in[2];
    const float* W0 = (const float*)d_in[3];
    const float* b0 = (const float*)d_in[4];
    const float* g0 = (const float*)d_in[5];
    const float* bb0 = (const float*)d_in[6];
    const float* m0 = (const float*)d_in[7];
    const float* v0 = (const float*)d_in[8];
    const float* W1 = (const float*)d_in[9];
    const float* b1 = (const float*)d_in[10];
    const float* g1 = (const float*)d_in[11];
    const float* bb1 = (const float*)d_in[12];
    const float* m1 = (const float*)d_in[13];
    const float* v1 = (const float*)d_in[14];
    const float* hW1 = (const float*)d_in[15];
    const float* hb1 = (const float*)d_in[16];
    const float* hg1 = (const float*)d_in[17];
    const float* hbb1 = (const float*)d_in[18];
    const float* hm1 = (const float*)d_in[19];
    const float* hv1 = (const float*)d_in[20];
    const float* hW2 = (const float*)d_in[21];
    const float* hb2 = (const float*)d_in[22];
    const float* hg2 = (const float*)d_in[23];
    const float* hbb2 = (const float*)d_in[24];
    const float* hm2 = (const float*)d_in[25];
    const float* hv2 = (const float*)d_in[26];
    const float* hW3 = (const float*)d_in[27];
    const float* hb3 = (const float*)d_in[28];
    const float* hW4 = (const float*)d_in[29];
    const float* hb4 = (const float*)d_in[30];
    float* out = (float*)d_out;

    // workspace layout (16B-aligned pieces)
    __half* xwhA = (__half*)d_ws;                            // N*64 fp16 (table0 / table1)
    __half* xwhB = xwhA + (size_t)N_NODES * D;               // N*64 fp16 (h0)
    float*  bufB = (float*)(xwhB + (size_t)N_NODES * D);     // N*64 f32 (h1 for head)
    int*    cnt  = (int*)(bufB + (size_t)N_NODES * D);       // N ints (in-degree)
    unsigned short* ssrc = (unsigned short*)(cnt + N_NODES); // N*cap ushorts

    size_t used = (size_t)2 * N_NODES * D * 2 + (size_t)N_NODES * D * 4
                + (size_t)N_NODES * 4;
    int cap = 64;
    if (ws_size >= used) {
        size_t avail = (ws_size - used) / ((size_t)N_NODES * 2);
        if (avail < (size_t)cap) cap = (int)avail & ~7;
    } else {
        cap = 0;
    }

    const int NT = 256;
    hipMemsetAsync(cnt, 0, (size_t)N_NODES * 4, stream);

    // 1) gemm0 ∥ CSR build (unscaled fp16 table — no cnt dependency)
    build_gemm_kernel<<<SCAT_GRID + GEMM_BLOCKS, NT, 0, stream>>>(
        ei, cnt, ssrc, cap, x, W0, xwhA);

    // 2) agg0 + BN + ReLU -> h0 (fp16)
    agg_bn_kernel<true><<<(N_NODES * 64) / NT, NT, 0, stream>>>(
        xwhA, cnt, ssrc, cap, b0, g0, bb0, m0, v0, xwhB, N_NODES);

    // 3) gemm1 (fp16 in, fp16 out, unscaled) -> table1
    gemm64h_kernel<<<GEMM_BLOCKS, NT, 0, stream>>>(xwhB, W1, xwhA, N_NODES);

    // 4) agg1 + BN + ReLU -> h1 (f32)
    agg_bn_kernel<false><<<(N_NODES * 64) / NT, NT, 0, stream>>>(
        xwhA, cnt, ssrc, cap, b1, g1, bb1, m1, v1, bufB, N_NODES);

    // 5) mean pool + MLP head (fused)
    pool_head_kernel<<<NUM_GRAPHS, NT, 0, stream>>>(bufB, batch,
        hW1, hb1, hg1, hbb1, hm1, hv1,
        hW2, hb2, hg2, hbb2, hm2, hv2,
        hW3, hb3, hW4, hb4, out);
}